// Round 5
// baseline (4081.217 us; speedup 1.0000x reference)
//
#include <hip/hip_runtime.h>
#include <stdint.h>

typedef __attribute__((ext_vector_type(4))) float f32x4;
typedef _Float16 f16x8 __attribute__((ext_vector_type(8)));
typedef __attribute__((ext_vector_type(2))) unsigned int u32x2;
typedef unsigned short u16;
typedef unsigned int u32;

#define LSEQ 8192
#define BB 8
#define DD 1024
#define MM 65536      // B*L
#define NCH 128       // chunks per sequence (L/64)

__device__ __forceinline__ u16 f2h(float f) {
    _Float16 h = (_Float16)f;
    return *(u16*)&h;
}
__device__ __forceinline__ float h2f(u16 u) {
    _Float16 h = *(_Float16*)&u;
    return (float)h;
}

__device__ __forceinline__ void gload_lds16(const void* g, void* l) {
    __builtin_amdgcn_global_load_lds(
        (const __attribute__((address_space(1))) u32*)g,
        (__attribute__((address_space(3))) u32*)l, 16, 0, 0);
}

// ---------------- conv + silu + transpose -> xb f16 [B*L][D] ----------------
__global__ __launch_bounds__(256) void k_conv_silu(const float* __restrict__ x,
                                                   const float* __restrict__ w,
                                                   u16* __restrict__ xb) {
    int m = blockIdx.x;              // m = b*L + l
    int b = m >> 13, l = m & 8191;
    int d0 = threadIdx.x * 4;
    f32x4 wv[4];
#pragma unroll
    for (int j = 0; j < 4; j++) wv[j] = *(const f32x4*)&w[(d0 + j) * 4];
    float acc[4] = {0.f, 0.f, 0.f, 0.f};
#pragma unroll
    for (int kk = 0; kk < 4; kk++) {
        int lp = l - 3 + kk;
        if (lp >= 0) {
            f32x4 xv = *(const f32x4*)&x[((size_t)(lp * BB + b)) * DD + d0];
#pragma unroll
            for (int j = 0; j < 4; j++) acc[j] += xv[j] * wv[j][kk];
        }
    }
    u16 o[4];
#pragma unroll
    for (int j = 0; j < 4; j++) {
        float a = acc[j];
        o[j] = f2h(a / (1.f + __expf(-a)));
    }
    u32x2 pk;
    pk.x = (u32)o[0] | ((u32)o[1] << 16);
    pk.y = (u32)o[2] | ((u32)o[3] << 16);
    *(u32x2*)&xb[(size_t)m * DD + d0] = pk;
}

// ---------------- pack weights into B^T f16 layouts ----------------
__global__ __launch_bounds__(256) void k_packW(const float* __restrict__ Wq,
                                               const float* __restrict__ Wkg,
                                               const float* __restrict__ Wv,
                                               const float* __restrict__ Wg,
                                               const float* __restrict__ Wout,
                                               u16* __restrict__ Wcat,
                                               u16* __restrict__ WoutT) {
    int idx = blockIdx.x * 256 + threadIdx.x;
    const int T1 = 3072 * 1024;
    if (idx < T1) {
        int n = idx >> 10, kk = idx & 1023;
        float v;
        if (n < 512)        v = Wq [kk * 512 + n];
        else if (n < 1024)  v = Wkg[kk * 512 + (n - 512)];
        else if (n < 2048)  v = Wv [kk * 1024 + (n - 1024)];
        else                v = Wg [kk * 1024 + (n - 2048)];
        Wcat[idx] = f2h(v);
    } else {
        int j = idx - T1;
        if (j < 1024 * 1024) {
            int n = j >> 10, kk = j & 1023;
            WoutT[j] = f2h(Wout[kk * 1024 + n]);
        }
    }
}

// ---------------- f16 GEMM, C = A[M][K] * Bt[N][K]^T, 256x256 tile, BK=64 ----------------
// 512 threads = 8 waves (2 M x 4 N); per-wave 128x64; double-buffered 128 KB LDS;
// T2 XOR-swizzle (linear gload_lds dest + pre-swizzled global src + swizzled read);
// T3-minimum: STAGE(t+1) issued before compute(t), one barrier (+implicit vmcnt0) per K-tile.
// 2D-blocked XCD ordering: chunk = 32 m-tiles x nt_tiles; within chunk, m-groups of 4, n-sweep.
// MODE 1: fused projection epilogue (q/gk/k/v/sg all f16)
// MODE 2: output GEMM with [B,L,D]->[L,B,D] scatter (fp32)
template <int MODE>
__global__ __launch_bounds__(512, 2) void k_gemm_bt(
    const u16* __restrict__ A, const u16* __restrict__ Bt, int nt_tiles,
    u16* __restrict__ qo, u16* __restrict__ gko, u16* __restrict__ ko,
    u16* __restrict__ vo, u16* __restrict__ sgo, const float* __restrict__ bg,
    float* __restrict__ out) {
    const int K = 1024;
    __shared__ __align__(16) u16 Sm[65536];   // 128 KB: [2 buf][A 32KB | B 32KB]
    int tid = threadIdx.x;
    int w = tid >> 6, lane = tid & 63;
    int wm = w >> 2, wn = w & 3;
    int lr = lane & 15, lk = lane >> 4;

    // XCD-aware 2D-blocked tile mapping
    int xcd = blockIdx.x & 7;
    int cidx = blockIdx.x >> 3;
    int grpsz = nt_tiles * 4;
    int grp = cidx / grpsz;
    int r = cidx - grp * grpsz;
    int ntile = r >> 2;
    int mts_per_chunk = (gridDim.x >> 3) / nt_tiles;   // 32
    int mtile = xcd * mts_per_chunk + grp * 4 + (r & 3);
    int m0 = mtile << 8, n0 = ntile << 8;

    f32x4 acc[8][4];
#pragma unroll
    for (int i = 0; i < 8; i++)
#pragma unroll
        for (int j = 0; j < 4; j++) acc[i][j] = {0.f, 0.f, 0.f, 0.f};

    // pre-swizzled global source: 16B slot (lane&7) ^ (row&7), row&7 = lane>>3
    int slot = (lane & 7) ^ ((lane >> 3) & 7);
    const u16* gA = A + (size_t)(m0 + w * 32 + (lane >> 3)) * K + slot * 8;
    const u16* gB = Bt + (size_t)(n0 + w * 32 + (lane >> 3)) * K + slot * 8;
    char* lA = (char*)Sm + w * 4096;            // + buf*65536 ; HW adds lane*16
    char* lB = (char*)Sm + 32768 + w * 4096;

    // prologue: stage K-tile 0 into buf 0
#pragma unroll
    for (int p = 0; p < 4; p++) {
        gload_lds16(gA + (size_t)(p * 8) * K, lA + p * 1024);
        gload_lds16(gB + (size_t)(p * 8) * K, lB + p * 1024);
    }
    __syncthreads();

    int buf = 0;
    for (int t = 0; t < 16; ++t) {
        if (t < 15) {
            int k1 = (t + 1) << 6;
            int ob = (buf ^ 1) * 65536;
#pragma unroll
            for (int p = 0; p < 4; p++) {
                gload_lds16(gA + (size_t)(p * 8) * K + k1, lA + ob + p * 1024);
                gload_lds16(gB + (size_t)(p * 8) * K + k1, lB + ob + p * 1024);
            }
        }
        const u16* As = Sm + buf * 32768;
        const u16* Bs = As + 16384;
        __builtin_amdgcn_s_setprio(1);
#pragma unroll
        for (int ks = 0; ks < 2; ks++) {
            int csl = ((ks * 4 + lk) ^ (lr & 7)) * 8;
            f16x8 bfr[4];
#pragma unroll
            for (int nt = 0; nt < 4; nt++)
                bfr[nt] = *(const f16x8*)&Bs[(wn * 64 + nt * 16 + lr) * 64 + csl];
#pragma unroll
            for (int mt = 0; mt < 8; mt++) {
                f16x8 a = *(const f16x8*)&As[(wm * 128 + mt * 16 + lr) * 64 + csl];
#pragma unroll
                for (int nt = 0; nt < 4; nt++)
                    acc[mt][nt] = __builtin_amdgcn_mfma_f32_16x16x32_f16(a, bfr[nt], acc[mt][nt], 0, 0, 0);
            }
        }
        __builtin_amdgcn_s_setprio(0);
        __syncthreads();   // compiler-inserted vmcnt(0)+lgkmcnt(0) drains stage(t+1)
        buf ^= 1;
    }

#pragma unroll
    for (int mt = 0; mt < 8; mt++) {
#pragma unroll
        for (int nt = 0; nt < 4; nt++) {
            int gcol = n0 + wn * 64 + nt * 16 + lr;
#pragma unroll
            for (int rr = 0; rr < 4; rr++) {
                int grow = m0 + wm * 128 + mt * 16 + lk * 4 + rr;
                float val = acc[mt][nt][rr];
                if (MODE == 1) {
                    if (gcol < 512) {
                        qo[(size_t)grow * 512 + gcol] = f2h(val);
                    } else if (gcol < 1024) {
                        float ls = fminf(val, 0.f) - log1pf(__expf(-fabsf(val)));
                        float gkv = ls * 0.0625f;
                        gko[(size_t)grow * 512 + (gcol - 512)] = f2h(gkv);
                        ko [(size_t)grow * 512 + (gcol - 512)] = f2h(-expm1f(gkv));
                    } else if (gcol < 2048) {
                        vo[(size_t)grow * 1024 + (gcol - 1024)] = f2h(val);
                    } else {
                        float gg = val + bg[gcol - 2048];
                        sgo[(size_t)grow * 1024 + (gcol - 2048)] = f2h(gg / (1.f + __expf(-gg)));
                    }
                } else {
                    int l = grow & 8191, b = grow >> 13;
                    out[((size_t)(l * BB + b)) * DD + gcol] = val;
                }
            }
        }
    }
}

// ---------------- pass1: per-chunk increment M_c = sum_s k_s e^{G_C - G_s} v_s^T ----------------
__global__ __launch_bounds__(64) void k_pass1(const u16* __restrict__ gkb,
                                              const u16* __restrict__ kb,
                                              const u16* __restrict__ vb,
                                              float* __restrict__ Mo,
                                              float* __restrict__ eGC) {
    __shared__ __align__(16) float kkT[64 * 32];  // [t][i] fp32
    int bhc = blockIdx.x;
    int c = bhc & 127, bh = bhc >> 7;
    int h = bh & 15, b = bh >> 4;
    int m0 = b * LSEQ + c * 64;
    int lane = threadIdx.x;
    if (lane < 32) {
        int i = lane;
        size_t base = (size_t)m0 * 512 + h * 32 + i;
        float G = 0.f;
        for (int t = 0; t < 64; t++) {
            G += h2f(gkb[base + (size_t)t * 512]);
            G = fmaxf(G, -60.f);
            kkT[t * 32 + i] = h2f(kb[base + (size_t)t * 512]) * __expf(-G);
        }
        eGC[bhc * 32 + i] = __expf(G);
    }
    __syncthreads();
    float Ma[32];
#pragma unroll
    for (int i = 0; i < 32; i++) Ma[i] = 0.f;
    size_t vbase = (size_t)m0 * 1024 + h * 64 + lane;
    for (int t = 0; t < 64; t++) {
        float vj = h2f(vb[vbase + (size_t)t * 1024]);
#pragma unroll
        for (int i4 = 0; i4 < 32; i4 += 4) {
            f32x4 kk4 = *(const f32x4*)&kkT[t * 32 + i4];
            Ma[i4 + 0] += kk4[0] * vj;
            Ma[i4 + 1] += kk4[1] * vj;
            Ma[i4 + 2] += kk4[2] * vj;
            Ma[i4 + 3] += kk4[3] * vj;
        }
    }
    size_t mb = (size_t)bhc * 2048 + lane;
#pragma unroll
    for (int i = 0; i < 32; i++) Mo[mb + i * 64] = Ma[i];
}

// ---------------- pass2: chunk-level recurrence (sequential over 128 chunks) ----------------
__global__ __launch_bounds__(64) void k_pass2(float* Mbuf, float* Sbuf,
                                              const float* __restrict__ eGC,
                                              float* __restrict__ state_out, int aliased) {
    int bh = blockIdx.x;
    int j = threadIdx.x;
    float S[32];
#pragma unroll
    for (int i = 0; i < 32; i++) S[i] = 0.f;
    for (int c = 0; c < NCH; c++) {
        size_t base = ((size_t)bh * NCH + c) * 2048;
        float mv[32], ev[32];
#pragma unroll
        for (int i = 0; i < 32; i++) mv[i] = Mbuf[base + i * 64 + j];
#pragma unroll
        for (int i = 0; i < 32; i++) ev[i] = eGC[(bh * NCH + c) * 32 + i];
        if (aliased) { asm volatile("s_waitcnt vmcnt(0)" ::: "memory"); }
#pragma unroll
        for (int i = 0; i < 32; i++) Sbuf[base + i * 64 + j] = S[i];  // chunk-START state
#pragma unroll
        for (int i = 0; i < 32; i++) S[i] = (S[i] + mv[i]) * ev[i];
    }
    size_t so = (size_t)bh * 2048 + j;
#pragma unroll
    for (int i = 0; i < 32; i++) state_out[so + i * 64] = S[i];
}

// ---------------- pass3: intra-chunk outputs + aug + groupnorm + silu-gate ----------------
__global__ __launch_bounds__(64) void k_pass3(const u16* __restrict__ qb,
                                              const u16* __restrict__ gkb,
                                              const u16* __restrict__ kb,
                                              const u16* __restrict__ vb,
                                              const u16* __restrict__ sgb,
                                              const float* __restrict__ Sbuf,
                                              const float* __restrict__ aug,
                                              u16* __restrict__ PRE) {
    __shared__ __align__(16) float qqT[64 * 32];  // [t][i] fp32
    __shared__ __align__(16) float kkT[64 * 32];
    __shared__ float awl[64];
    int bhc = blockIdx.x;
    int c = bhc & 127, bh = bhc >> 7;
    int h = bh & 15, b = bh >> 4;
    int m0 = b * LSEQ + c * 64;
    int lane = threadIdx.x;
    const float scale = 0.17677669529663689f;  // 1/sqrt(32)
    if (lane < 32) {
        int i = lane;
        float augi = aug[h * 32 + i];
        size_t base = (size_t)m0 * 512 + h * 32 + i;
        float G = 0.f;
        for (int t = 0; t < 64; t++) {
            float gkv = h2f(gkb[base + (size_t)t * 512]);
            float qv  = h2f(qb [base + (size_t)t * 512]);
            float kv  = h2f(kb [base + (size_t)t * 512]);
            G += gkv;
            G = fmaxf(G, -60.f);
            float en = __expf(-G);
            float ep = __expf(G);
            qqT[t * 32 + i] = qv * ep * scale;
            kkT[t * 32 + i] = kv * en;
            float p = qv * kv * augi;  // aug uses raw q,k
            p += __shfl_xor(p, 1);
            p += __shfl_xor(p, 2);
            p += __shfl_xor(p, 4);
            p += __shfl_xor(p, 8);
            p += __shfl_xor(p, 16);
            if (i == 0) awl[t] = p;
        }
    }
    __syncthreads();
    float T[32];
    size_t sb = (size_t)bhc * 2048 + lane;
#pragma unroll
    for (int i = 0; i < 32; i++) T[i] = Sbuf[sb + i * 64];
    size_t vbase = (size_t)m0 * 1024 + h * 64 + lane;
    for (int t = 0; t < 64; t++) {
        float vj  = h2f(vb [vbase + (size_t)t * 1024]);
        float sgj = h2f(sgb[vbase + (size_t)t * 1024]);
        float aw = awl[t];
        float o = 0.f;
#pragma unroll
        for (int i4 = 0; i4 < 32; i4 += 4) {
            f32x4 kk4 = *(const f32x4*)&kkT[t * 32 + i4];
            f32x4 qq4 = *(const f32x4*)&qqT[t * 32 + i4];
#pragma unroll
            for (int e = 0; e < 4; e++) {
                T[i4 + e] += kk4[e] * vj;    // T_t = S_c + sum kk v
                o += qq4[e] * T[i4 + e];     // o_t = qq_t . T_t
            }
        }
        o += 1.f / (1.f + __expf(-aw * vj));       // + sigmoid(aug_w * v)
        // group norm over dv=64 (all 64 lanes)
        float s1 = o, s2 = o * o;
#pragma unroll
        for (int msk = 1; msk < 64; msk <<= 1) {
            s1 += __shfl_xor(s1, msk);
            s2 += __shfl_xor(s2, msk);
        }
        float mu = s1 * 0.015625f;
        float var = s2 * 0.015625f - mu * mu;
        float on = (o - mu) * rsqrtf(fmaxf(var, 0.f) + 1e-5f);
        PRE[vbase + (size_t)t * 1024] = f2h(on * sgj);
    }
}

// ---------------- host launch ----------------
extern "C" void kernel_launch(void* const* d_in, const int* in_sizes, int n_in,
                              void* d_out, int out_size, void* d_ws, size_t ws_size,
                              hipStream_t stream) {
    (void)in_sizes; (void)n_in; (void)out_size;
    const float* x      = (const float*)d_in[0];
    const float* conv_w = (const float*)d_in[1];
    const float* Wq     = (const float*)d_in[2];
    const float* Wkg    = (const float*)d_in[3];
    const float* Wv     = (const float*)d_in[4];
    const float* Wg     = (const float*)d_in[5];
    const float* bg     = (const float*)d_in[6];
    const float* Wout   = (const float*)d_in[7];
    const float* aug    = (const float*)d_in[8];

    char* ws = (char*)d_ws;
    u16*   xb    = (u16*)  (ws + 0);            // 134217728 B (also PRE later)
    u16*   Wcat  = (u16*)  (ws + 134217728);    //   6291456
    u16*   WoutT = (u16*)  (ws + 140509184);    //   2097152
    u16*   qb    = (u16*)  (ws + 142606336);    //  67108864
    u16*   gkb   = (u16*)  (ws + 209715200);    //  67108864
    u16*   kbuf  = (u16*)  (ws + 276824064);    //  67108864
    u16*   sgb   = (u16*)  (ws + 343932928);    // 134217728
    float* Mbuf  = (float*)(ws + 478150656);    // 134217728
    float* eGC   = (float*)(ws + 612368384);    //   2097152
    float* Sb    = (float*)(ws + 614465536);    // 134217728 (optional)
    const size_t REQ_FULL = 748683264ull;
    int aliased = (ws_size < REQ_FULL) ? 1 : 0;
    float* Sbuf = aliased ? Mbuf : Sb;

    float* out = (float*)d_out;
    float* state_out = out + 67108864;
    u16* vb = (u16*)d_out;  // v (f16) lives in out region until GEMM2 overwrites it

    k_conv_silu<<<dim3(65536), dim3(256), 0, stream>>>(x, conv_w, xb);
    k_packW<<<dim3(16384), dim3(256), 0, stream>>>(Wq, Wkg, Wv, Wg, Wout, Wcat, WoutT);
    k_gemm_bt<1><<<dim3(3072), dim3(512), 0, stream>>>(xb, Wcat, 12,
                                                       qb, gkb, kbuf, vb, sgb, bg, nullptr);
    k_pass1<<<dim3(16384), dim3(64), 0, stream>>>(gkb, kbuf, vb, Mbuf, eGC);
    k_pass2<<<dim3(128), dim3(64), 0, stream>>>(Mbuf, Sbuf, eGC, state_out, aliased);
    k_pass3<<<dim3(16384), dim3(64), 0, stream>>>(qb, gkb, kbuf, vb, sgb, Sbuf, aug, xb /*PRE*/);
    k_gemm_bt<2><<<dim3(1024), dim3(512), 0, stream>>>(xb, WoutT, 4,
                                                       nullptr, nullptr, nullptr, nullptr, nullptr, nullptr, out);
}

// Round 6
// 4056.277 us; speedup vs baseline: 1.0061x; 1.0061x over previous
//
#include <hip/hip_runtime.h>
#include <stdint.h>

typedef __attribute__((ext_vector_type(4))) float f32x4;
typedef _Float16 f16x8 __attribute__((ext_vector_type(8)));
typedef __attribute__((ext_vector_type(2))) unsigned int u32x2;
typedef unsigned short u16;
typedef unsigned int u32;

#define LSEQ 8192
#define BB 8
#define DD 1024
#define MM 65536      // B*L
#define NCH 128       // chunks per sequence (L/64)

__device__ __forceinline__ u16 f2h(float f) {
    _Float16 h = (_Float16)f;
    return *(u16*)&h;
}
__device__ __forceinline__ float h2f(u16 u) {
    _Float16 h = *(_Float16*)&u;
    return (float)h;
}

__device__ __forceinline__ void gload_lds16(const void* g, void* l) {
    __builtin_amdgcn_global_load_lds(
        (const __attribute__((address_space(1))) u32*)g,
        (__attribute__((address_space(3))) u32*)l, 16, 0, 0);
}

// ---------------- conv + silu + transpose -> xb f16 [B*L][D] ----------------
__global__ __launch_bounds__(256) void k_conv_silu(const float* __restrict__ x,
                                                   const float* __restrict__ w,
                                                   u16* __restrict__ xb) {
    int m = blockIdx.x;              // m = b*L + l
    int b = m >> 13, l = m & 8191;
    int d0 = threadIdx.x * 4;
    f32x4 wv[4];
#pragma unroll
    for (int j = 0; j < 4; j++) wv[j] = *(const f32x4*)&w[(d0 + j) * 4];
    float acc[4] = {0.f, 0.f, 0.f, 0.f};
#pragma unroll
    for (int kk = 0; kk < 4; kk++) {
        int lp = l - 3 + kk;
        if (lp >= 0) {
            f32x4 xv = *(const f32x4*)&x[((size_t)(lp * BB + b)) * DD + d0];
#pragma unroll
            for (int j = 0; j < 4; j++) acc[j] += xv[j] * wv[j][kk];
        }
    }
    u16 o[4];
#pragma unroll
    for (int j = 0; j < 4; j++) {
        float a = acc[j];
        o[j] = f2h(a / (1.f + __expf(-a)));
    }
    u32x2 pk;
    pk.x = (u32)o[0] | ((u32)o[1] << 16);
    pk.y = (u32)o[2] | ((u32)o[3] << 16);
    *(u32x2*)&xb[(size_t)m * DD + d0] = pk;
}

// ---------------- pack weights into B^T f16 layouts ----------------
__global__ __launch_bounds__(256) void k_packW(const float* __restrict__ Wq,
                                               const float* __restrict__ Wkg,
                                               const float* __restrict__ Wv,
                                               const float* __restrict__ Wg,
                                               const float* __restrict__ Wout,
                                               u16* __restrict__ Wcat,
                                               u16* __restrict__ WoutT) {
    int idx = blockIdx.x * 256 + threadIdx.x;
    const int T1 = 3072 * 1024;
    if (idx < T1) {
        int n = idx >> 10, kk = idx & 1023;
        float v;
        if (n < 512)        v = Wq [kk * 512 + n];
        else if (n < 1024)  v = Wkg[kk * 512 + (n - 512)];
        else if (n < 2048)  v = Wv [kk * 1024 + (n - 1024)];
        else                v = Wg [kk * 1024 + (n - 2048)];
        Wcat[idx] = f2h(v);
    } else {
        int j = idx - T1;
        if (j < 1024 * 1024) {
            int n = j >> 10, kk = j & 1023;
            WoutT[j] = f2h(Wout[kk * 1024 + n]);
        }
    }
}

// ---------------- f16 GEMM, C = A[M][K] * Bt[N][K]^T, 256x256 tile, BK=64 ----------------
// 512 threads = 8 waves (2 M x 4 N); per-wave 128x64; double-buffered 128 KB LDS;
// T2 XOR-swizzle (linear gload_lds dest + pre-swizzled global src + swizzled read);
// T3-minimum: STAGE(t+1) issued before compute(t), one barrier (+implicit vmcnt0) per K-tile.
// 2D-blocked XCD ordering: chunk = 32 m-tiles x nt_tiles; within chunk, m-groups of 4, n-sweep.
// __launch_bounds__(512, 1): R5 post-mortem — (512,2) capped VGPR at 88 and spilled
// the 128-VGPR accumulator to scratch (WRITE_SIZE 13.9 GB, 3x slowdown).
// MODE 1: fused projection epilogue (q/gk/k/v/sg all f16)
// MODE 2: output GEMM with [B,L,D]->[L,B,D] scatter (fp32)
template <int MODE>
__global__ __launch_bounds__(512, 1) void k_gemm_bt(
    const u16* __restrict__ A, const u16* __restrict__ Bt, int nt_tiles,
    u16* __restrict__ qo, u16* __restrict__ gko, u16* __restrict__ ko,
    u16* __restrict__ vo, u16* __restrict__ sgo, const float* __restrict__ bg,
    float* __restrict__ out) {
    const int K = 1024;
    __shared__ __align__(16) u16 Sm[65536];   // 128 KB: [2 buf][A 32KB | B 32KB]
    int tid = threadIdx.x;
    int w = tid >> 6, lane = tid & 63;
    int wm = w >> 2, wn = w & 3;
    int lr = lane & 15, lk = lane >> 4;

    // XCD-aware 2D-blocked tile mapping
    int xcd = blockIdx.x & 7;
    int cidx = blockIdx.x >> 3;
    int grpsz = nt_tiles * 4;
    int grp = cidx / grpsz;
    int r = cidx - grp * grpsz;
    int ntile = r >> 2;
    int mts_per_chunk = (gridDim.x >> 3) / nt_tiles;   // 32
    int mtile = xcd * mts_per_chunk + grp * 4 + (r & 3);
    int m0 = mtile << 8, n0 = ntile << 8;

    f32x4 acc[8][4];
#pragma unroll
    for (int i = 0; i < 8; i++)
#pragma unroll
        for (int j = 0; j < 4; j++) acc[i][j] = {0.f, 0.f, 0.f, 0.f};

    // pre-swizzled global source: 16B slot (lane&7) ^ (row&7), row&7 = lane>>3
    int slot = (lane & 7) ^ ((lane >> 3) & 7);
    const u16* gA = A + (size_t)(m0 + w * 32 + (lane >> 3)) * K + slot * 8;
    const u16* gB = Bt + (size_t)(n0 + w * 32 + (lane >> 3)) * K + slot * 8;
    char* lA = (char*)Sm + w * 4096;            // + buf*65536 ; HW adds lane*16
    char* lB = (char*)Sm + 32768 + w * 4096;

    // prologue: stage K-tile 0 into buf 0
#pragma unroll
    for (int p = 0; p < 4; p++) {
        gload_lds16(gA + (size_t)(p * 8) * K, lA + p * 1024);
        gload_lds16(gB + (size_t)(p * 8) * K, lB + p * 1024);
    }
    __syncthreads();

    int buf = 0;
    for (int t = 0; t < 16; ++t) {
        if (t < 15) {
            int k1 = (t + 1) << 6;
            int ob = (buf ^ 1) * 65536;
#pragma unroll
            for (int p = 0; p < 4; p++) {
                gload_lds16(gA + (size_t)(p * 8) * K + k1, lA + ob + p * 1024);
                gload_lds16(gB + (size_t)(p * 8) * K + k1, lB + ob + p * 1024);
            }
        }
        const u16* As = Sm + buf * 32768;
        const u16* Bs = As + 16384;
        __builtin_amdgcn_s_setprio(1);
#pragma unroll
        for (int ks = 0; ks < 2; ks++) {
            int csl = ((ks * 4 + lk) ^ (lr & 7)) * 8;
            f16x8 bfr[4];
#pragma unroll
            for (int nt = 0; nt < 4; nt++)
                bfr[nt] = *(const f16x8*)&Bs[(wn * 64 + nt * 16 + lr) * 64 + csl];
#pragma unroll
            for (int mt = 0; mt < 8; mt++) {
                f16x8 a = *(const f16x8*)&As[(wm * 128 + mt * 16 + lr) * 64 + csl];
#pragma unroll
                for (int nt = 0; nt < 4; nt++)
                    acc[mt][nt] = __builtin_amdgcn_mfma_f32_16x16x32_f16(a, bfr[nt], acc[mt][nt], 0, 0, 0);
            }
        }
        __builtin_amdgcn_s_setprio(0);
        __syncthreads();   // compiler-inserted vmcnt(0)+lgkmcnt(0) drains stage(t+1)
        buf ^= 1;
    }

#pragma unroll
    for (int mt = 0; mt < 8; mt++) {
#pragma unroll
        for (int nt = 0; nt < 4; nt++) {
            int gcol = n0 + wn * 64 + nt * 16 + lr;
#pragma unroll
            for (int rr = 0; rr < 4; rr++) {
                int grow = m0 + wm * 128 + mt * 16 + lk * 4 + rr;
                float val = acc[mt][nt][rr];
                if (MODE == 1) {
                    if (gcol < 512) {
                        qo[(size_t)grow * 512 + gcol] = f2h(val);
                    } else if (gcol < 1024) {
                        float ls = fminf(val, 0.f) - log1pf(__expf(-fabsf(val)));
                        float gkv = ls * 0.0625f;
                        gko[(size_t)grow * 512 + (gcol - 512)] = f2h(gkv);
                        ko [(size_t)grow * 512 + (gcol - 512)] = f2h(-expm1f(gkv));
                    } else if (gcol < 2048) {
                        vo[(size_t)grow * 1024 + (gcol - 1024)] = f2h(val);
                    } else {
                        float gg = val + bg[gcol - 2048];
                        sgo[(size_t)grow * 1024 + (gcol - 2048)] = f2h(gg / (1.f + __expf(-gg)));
                    }
                } else {
                    int l = grow & 8191, b = grow >> 13;
                    out[((size_t)(l * BB + b)) * DD + gcol] = val;
                }
            }
        }
    }
}

// ---------------- pass1: per-chunk increment M_c = sum_s k_s e^{G_C - G_s} v_s^T ----------------
__global__ __launch_bounds__(64) void k_pass1(const u16* __restrict__ gkb,
                                              const u16* __restrict__ kb,
                                              const u16* __restrict__ vb,
                                              float* __restrict__ Mo,
                                              float* __restrict__ eGC) {
    __shared__ __align__(16) float kkT[64 * 32];  // [t][i] fp32
    int bhc = blockIdx.x;
    int c = bhc & 127, bh = bhc >> 7;
    int h = bh & 15, b = bh >> 4;
    int m0 = b * LSEQ + c * 64;
    int lane = threadIdx.x;
    if (lane < 32) {
        int i = lane;
        size_t base = (size_t)m0 * 512 + h * 32 + i;
        float G = 0.f;
        for (int t = 0; t < 64; t++) {
            G += h2f(gkb[base + (size_t)t * 512]);
            G = fmaxf(G, -60.f);
            kkT[t * 32 + i] = h2f(kb[base + (size_t)t * 512]) * __expf(-G);
        }
        eGC[bhc * 32 + i] = __expf(G);
    }
    __syncthreads();
    float Ma[32];
#pragma unroll
    for (int i = 0; i < 32; i++) Ma[i] = 0.f;
    size_t vbase = (size_t)m0 * 1024 + h * 64 + lane;
    for (int t = 0; t < 64; t++) {
        float vj = h2f(vb[vbase + (size_t)t * 1024]);
#pragma unroll
        for (int i4 = 0; i4 < 32; i4 += 4) {
            f32x4 kk4 = *(const f32x4*)&kkT[t * 32 + i4];
            Ma[i4 + 0] += kk4[0] * vj;
            Ma[i4 + 1] += kk4[1] * vj;
            Ma[i4 + 2] += kk4[2] * vj;
            Ma[i4 + 3] += kk4[3] * vj;
        }
    }
    size_t mb = (size_t)bhc * 2048 + lane;
#pragma unroll
    for (int i = 0; i < 32; i++) Mo[mb + i * 64] = Ma[i];
}

// ---------------- pass2: chunk-level recurrence (sequential over 128 chunks) ----------------
__global__ __launch_bounds__(64) void k_pass2(float* Mbuf, float* Sbuf,
                                              const float* __restrict__ eGC,
                                              float* __restrict__ state_out, int aliased) {
    int bh = blockIdx.x;
    int j = threadIdx.x;
    float S[32];
#pragma unroll
    for (int i = 0; i < 32; i++) S[i] = 0.f;
    for (int c = 0; c < NCH; c++) {
        size_t base = ((size_t)bh * NCH + c) * 2048;
        float mv[32], ev[32];
#pragma unroll
        for (int i = 0; i < 32; i++) mv[i] = Mbuf[base + i * 64 + j];
#pragma unroll
        for (int i = 0; i < 32; i++) ev[i] = eGC[(bh * NCH + c) * 32 + i];
        if (aliased) { asm volatile("s_waitcnt vmcnt(0)" ::: "memory"); }
#pragma unroll
        for (int i = 0; i < 32; i++) Sbuf[base + i * 64 + j] = S[i];  // chunk-START state
#pragma unroll
        for (int i = 0; i < 32; i++) S[i] = (S[i] + mv[i]) * ev[i];
    }
    size_t so = (size_t)bh * 2048 + j;
#pragma unroll
    for (int i = 0; i < 32; i++) state_out[so + i * 64] = S[i];
}

// ---------------- pass3: intra-chunk outputs + aug + groupnorm + silu-gate ----------------
__global__ __launch_bounds__(64) void k_pass3(const u16* __restrict__ qb,
                                              const u16* __restrict__ gkb,
                                              const u16* __restrict__ kb,
                                              const u16* __restrict__ vb,
                                              const u16* __restrict__ sgb,
                                              const float* __restrict__ Sbuf,
                                              const float* __restrict__ aug,
                                              u16* __restrict__ PRE) {
    __shared__ __align__(16) float qqT[64 * 32];  // [t][i] fp32
    __shared__ __align__(16) float kkT[64 * 32];
    __shared__ float awl[64];
    int bhc = blockIdx.x;
    int c = bhc & 127, bh = bhc >> 7;
    int h = bh & 15, b = bh >> 4;
    int m0 = b * LSEQ + c * 64;
    int lane = threadIdx.x;
    const float scale = 0.17677669529663689f;  // 1/sqrt(32)
    if (lane < 32) {
        int i = lane;
        float augi = aug[h * 32 + i];
        size_t base = (size_t)m0 * 512 + h * 32 + i;
        float G = 0.f;
        for (int t = 0; t < 64; t++) {
            float gkv = h2f(gkb[base + (size_t)t * 512]);
            float qv  = h2f(qb [base + (size_t)t * 512]);
            float kv  = h2f(kb [base + (size_t)t * 512]);
            G += gkv;
            G = fmaxf(G, -60.f);
            float en = __expf(-G);
            float ep = __expf(G);
            qqT[t * 32 + i] = qv * ep * scale;
            kkT[t * 32 + i] = kv * en;
            float p = qv * kv * augi;  // aug uses raw q,k
            p += __shfl_xor(p, 1);
            p += __shfl_xor(p, 2);
            p += __shfl_xor(p, 4);
            p += __shfl_xor(p, 8);
            p += __shfl_xor(p, 16);
            if (i == 0) awl[t] = p;
        }
    }
    __syncthreads();
    float T[32];
    size_t sb = (size_t)bhc * 2048 + lane;
#pragma unroll
    for (int i = 0; i < 32; i++) T[i] = Sbuf[sb + i * 64];
    size_t vbase = (size_t)m0 * 1024 + h * 64 + lane;
    for (int t = 0; t < 64; t++) {
        float vj  = h2f(vb [vbase + (size_t)t * 1024]);
        float sgj = h2f(sgb[vbase + (size_t)t * 1024]);
        float aw = awl[t];
        float o = 0.f;
#pragma unroll
        for (int i4 = 0; i4 < 32; i4 += 4) {
            f32x4 kk4 = *(const f32x4*)&kkT[t * 32 + i4];
            f32x4 qq4 = *(const f32x4*)&qqT[t * 32 + i4];
#pragma unroll
            for (int e = 0; e < 4; e++) {
                T[i4 + e] += kk4[e] * vj;    // T_t = S_c + sum kk v
                o += qq4[e] * T[i4 + e];     // o_t = qq_t . T_t
            }
        }
        o += 1.f / (1.f + __expf(-aw * vj));       // + sigmoid(aug_w * v)
        // group norm over dv=64 (all 64 lanes)
        float s1 = o, s2 = o * o;
#pragma unroll
        for (int msk = 1; msk < 64; msk <<= 1) {
            s1 += __shfl_xor(s1, msk);
            s2 += __shfl_xor(s2, msk);
        }
        float mu = s1 * 0.015625f;
        float var = s2 * 0.015625f - mu * mu;
        float on = (o - mu) * rsqrtf(fmaxf(var, 0.f) + 1e-5f);
        PRE[vbase + (size_t)t * 1024] = f2h(on * sgj);
    }
}

// ---------------- host launch ----------------
extern "C" void kernel_launch(void* const* d_in, const int* in_sizes, int n_in,
                              void* d_out, int out_size, void* d_ws, size_t ws_size,
                              hipStream_t stream) {
    (void)in_sizes; (void)n_in; (void)out_size;
    const float* x      = (const float*)d_in[0];
    const float* conv_w = (const float*)d_in[1];
    const float* Wq     = (const float*)d_in[2];
    const float* Wkg    = (const float*)d_in[3];
    const float* Wv     = (const float*)d_in[4];
    const float* Wg     = (const float*)d_in[5];
    const float* bg     = (const float*)d_in[6];
    const float* Wout   = (const float*)d_in[7];
    const float* aug    = (const float*)d_in[8];

    char* ws = (char*)d_ws;
    u16*   xb    = (u16*)  (ws + 0);            // 134217728 B (also PRE later)
    u16*   Wcat  = (u16*)  (ws + 134217728);    //   6291456
    u16*   WoutT = (u16*)  (ws + 140509184);    //   2097152
    u16*   qb    = (u16*)  (ws + 142606336);    //  67108864
    u16*   gkb   = (u16*)  (ws + 209715200);    //  67108864
    u16*   kbuf  = (u16*)  (ws + 276824064);    //  67108864
    u16*   sgb   = (u16*)  (ws + 343932928);    // 134217728
    float* Mbuf  = (float*)(ws + 478150656);    // 134217728
    float* eGC   = (float*)(ws + 612368384);    //   2097152
    float* Sb    = (float*)(ws + 614465536);    // 134217728 (optional)
    const size_t REQ_FULL = 748683264ull;
    int aliased = (ws_size < REQ_FULL) ? 1 : 0;
    float* Sbuf = aliased ? Mbuf : Sb;

    float* out = (float*)d_out;
    float* state_out = out + 67108864;
    u16* vb = (u16*)d_out;  // v (f16) lives in out region until GEMM2 overwrites it

    k_conv_silu<<<dim3(65536), dim3(256), 0, stream>>>(x, conv_w, xb);
    k_packW<<<dim3(16384), dim3(256), 0, stream>>>(Wq, Wkg, Wv, Wg, Wout, Wcat, WoutT);
    k_gemm_bt<1><<<dim3(3072), dim3(512), 0, stream>>>(xb, Wcat, 12,
                                                       qb, gkb, kbuf, vb, sgb, bg, nullptr);
    k_pass1<<<dim3(16384), dim3(64), 0, stream>>>(gkb, kbuf, vb, Mbuf, eGC);
    k_pass2<<<dim3(128), dim3(64), 0, stream>>>(Mbuf, Sbuf, eGC, state_out, aliased);
    k_pass3<<<dim3(16384), dim3(64), 0, stream>>>(qb, gkb, kbuf, vb, sgb, Sbuf, aug, xb /*PRE*/);
    k_gemm_bt<2><<<dim3(1024), dim3(512), 0, stream>>>(xb, WoutT, 4,
                                                       nullptr, nullptr, nullptr, nullptr, nullptr, nullptr, out);
}

// Round 7
// 2123.229 us; speedup vs baseline: 1.9222x; 1.9104x over previous
//
#include <hip/hip_runtime.h>
#include <stdint.h>

typedef __attribute__((ext_vector_type(4))) float f32x4;
typedef _Float16 f16x8 __attribute__((ext_vector_type(8)));
typedef __attribute__((ext_vector_type(2))) unsigned int u32x2;
typedef unsigned short u16;
typedef unsigned int u32;

#define LSEQ 8192
#define BB 8
#define DD 1024
#define MM 65536      // B*L
#define NCH 128       // chunks per sequence (L/64)

__device__ __forceinline__ u16 f2h(float f) {
    _Float16 h = (_Float16)f;
    return *(u16*)&h;
}
__device__ __forceinline__ float h2f(u16 u) {
    _Float16 h = *(_Float16*)&u;
    return (float)h;
}

__device__ __forceinline__ void gload_lds16(const void* g, void* l) {
    __builtin_amdgcn_global_load_lds(
        (const __attribute__((address_space(1))) u32*)g,
        (__attribute__((address_space(3))) u32*)l, 16, 0, 0);
}

// ---------------- conv + silu + transpose -> xb f16 [B*L][D] ----------------
__global__ __launch_bounds__(256) void k_conv_silu(const float* __restrict__ x,
                                                   const float* __restrict__ w,
                                                   u16* __restrict__ xb) {
    int m = blockIdx.x;              // m = b*L + l
    int b = m >> 13, l = m & 8191;
    int d0 = threadIdx.x * 4;
    f32x4 wv[4];
#pragma unroll
    for (int j = 0; j < 4; j++) wv[j] = *(const f32x4*)&w[(d0 + j) * 4];
    float acc[4] = {0.f, 0.f, 0.f, 0.f};
#pragma unroll
    for (int kk = 0; kk < 4; kk++) {
        int lp = l - 3 + kk;
        if (lp >= 0) {
            f32x4 xv = *(const f32x4*)&x[((size_t)(lp * BB + b)) * DD + d0];
#pragma unroll
            for (int j = 0; j < 4; j++) acc[j] += xv[j] * wv[j][kk];
        }
    }
    u16 o[4];
#pragma unroll
    for (int j = 0; j < 4; j++) {
        float a = acc[j];
        o[j] = f2h(a / (1.f + __expf(-a)));
    }
    u32x2 pk;
    pk.x = (u32)o[0] | ((u32)o[1] << 16);
    pk.y = (u32)o[2] | ((u32)o[3] << 16);
    *(u32x2*)&xb[(size_t)m * DD + d0] = pk;
}

// ---------------- pack weights into B^T f16 layouts ----------------
__global__ __launch_bounds__(256) void k_packW(const float* __restrict__ Wq,
                                               const float* __restrict__ Wkg,
                                               const float* __restrict__ Wv,
                                               const float* __restrict__ Wg,
                                               const float* __restrict__ Wout,
                                               u16* __restrict__ Wcat,
                                               u16* __restrict__ WoutT) {
    int idx = blockIdx.x * 256 + threadIdx.x;
    const int T1 = 3072 * 1024;
    if (idx < T1) {
        int n = idx >> 10, kk = idx & 1023;
        float v;
        if (n < 512)        v = Wq [kk * 512 + n];
        else if (n < 1024)  v = Wkg[kk * 512 + (n - 512)];
        else if (n < 2048)  v = Wv [kk * 1024 + (n - 1024)];
        else                v = Wg [kk * 1024 + (n - 2048)];
        Wcat[idx] = f2h(v);
    } else {
        int j = idx - T1;
        if (j < 1024 * 1024) {
            int n = j >> 10, kk = j & 1023;
            WoutT[j] = f2h(Wout[kk * 1024 + n]);
        }
    }
}

// per-fragment epilogue (4 rows x 1 col-group of 16 handled by caller's lr)
template <int MODE>
__device__ __forceinline__ void epi_frag(f32x4 v, int grow0, int gcol,
                                         u16* __restrict__ qo, u16* __restrict__ gko,
                                         u16* __restrict__ ko, u16* __restrict__ vo,
                                         u16* __restrict__ sgo, const float* __restrict__ bg,
                                         float* __restrict__ out) {
#pragma unroll
    for (int rr = 0; rr < 4; rr++) {
        int grow = grow0 + rr;
        float val = v[rr];
        if (MODE == 1) {
            if (gcol < 512) {
                qo[(size_t)grow * 512 + gcol] = f2h(val);
            } else if (gcol < 1024) {
                float ls = fminf(val, 0.f) - log1pf(__expf(-fabsf(val)));
                float gkv = ls * 0.0625f;
                gko[(size_t)grow * 512 + (gcol - 512)] = f2h(gkv);
                ko [(size_t)grow * 512 + (gcol - 512)] = f2h(-expm1f(gkv));
            } else if (gcol < 2048) {
                vo[(size_t)grow * 1024 + (gcol - 1024)] = f2h(val);
            } else {
                float gg = val + bg[gcol - 2048];
                sgo[(size_t)grow * 1024 + (gcol - 2048)] = f2h(gg / (1.f + __expf(-gg)));
            }
        } else {
            int l = grow & 8191, b = grow >> 13;
            out[((size_t)(l * BB + b)) * DD + gcol] = val;
        }
    }
}

// ---------------- f16 GEMM, C = A[M][K] * Bt[N][K]^T, 256x256 tile, BK=64 ----------------
// 512 threads = 8 waves (2 M x 4 N); per-wave 128x64; double-buffered 128 KB LDS;
// T2 XOR-swizzle (linear gload_lds dest + pre-swizzled global src + swizzled read);
// STAGE(t+1) issued before compute(t), one barrier per K-tile.
// R6 post-mortem: f32x4 acc[8][4] was demoted to scratch (VGPR 88, 13.9 GB scratch
// writebacks) regardless of launch_bounds -> use 32 NAMED f32x4 accumulators (SSA).
template <int MODE>
__global__ __launch_bounds__(512) void k_gemm_bt(
    const u16* __restrict__ A, const u16* __restrict__ Bt, int nt_tiles,
    u16* __restrict__ qo, u16* __restrict__ gko, u16* __restrict__ ko,
    u16* __restrict__ vo, u16* __restrict__ sgo, const float* __restrict__ bg,
    float* __restrict__ out) {
    const int K = 1024;
    __shared__ __align__(16) u16 Sm[65536];   // 128 KB: [2 buf][A 32KB | B 32KB]
    int tid = threadIdx.x;
    int w = tid >> 6, lane = tid & 63;
    int wm = w >> 2, wn = w & 3;
    int lr = lane & 15, lk = lane >> 4;

    // XCD-aware 2D-blocked tile mapping
    int xcd = blockIdx.x & 7;
    int cidx = blockIdx.x >> 3;
    int grpsz = nt_tiles * 4;
    int grp = cidx / grpsz;
    int r = cidx - grp * grpsz;
    int ntile = r >> 2;
    int mts_per_chunk = (gridDim.x >> 3) / nt_tiles;   // 32
    int mtile = xcd * mts_per_chunk + grp * 4 + (r & 3);
    int m0 = mtile << 8, n0 = ntile << 8;

#define DECL_ACC(MT) f32x4 a##MT##_0 = {0.f,0.f,0.f,0.f}, a##MT##_1 = {0.f,0.f,0.f,0.f}, \
                           a##MT##_2 = {0.f,0.f,0.f,0.f}, a##MT##_3 = {0.f,0.f,0.f,0.f};
    DECL_ACC(0) DECL_ACC(1) DECL_ACC(2) DECL_ACC(3)
    DECL_ACC(4) DECL_ACC(5) DECL_ACC(6) DECL_ACC(7)
#undef DECL_ACC

    // pre-swizzled global source: 16B slot (lane&7) ^ (row&7), row&7 = lane>>3
    int slot = (lane & 7) ^ ((lane >> 3) & 7);
    const u16* gA = A + (size_t)(m0 + w * 32 + (lane >> 3)) * K + slot * 8;
    const u16* gB = Bt + (size_t)(n0 + w * 32 + (lane >> 3)) * K + slot * 8;
    char* lA = (char*)Sm + w * 4096;            // + buf*65536 ; HW adds lane*16
    char* lB = (char*)Sm + 32768 + w * 4096;

    // prologue: stage K-tile 0 into buf 0
#pragma unroll
    for (int p = 0; p < 4; p++) {
        gload_lds16(gA + (size_t)(p * 8) * K, lA + p * 1024);
        gload_lds16(gB + (size_t)(p * 8) * K, lB + p * 1024);
    }
    __syncthreads();

    int buf = 0;
    for (int t = 0; t < 16; ++t) {
        if (t < 15) {
            int k1 = (t + 1) << 6;
            int ob = (buf ^ 1) * 65536;
#pragma unroll
            for (int p = 0; p < 4; p++) {
                gload_lds16(gA + (size_t)(p * 8) * K + k1, lA + ob + p * 1024);
                gload_lds16(gB + (size_t)(p * 8) * K + k1, lB + ob + p * 1024);
            }
        }
        const u16* As = Sm + buf * 32768;
        const u16* Bs = As + 16384;
        __builtin_amdgcn_s_setprio(1);
#pragma unroll
        for (int ks = 0; ks < 2; ks++) {
            int csl = ((ks * 4 + lk) ^ (lr & 7)) * 8;
            f16x8 b0 = *(const f16x8*)&Bs[(wn * 64 +  0 + lr) * 64 + csl];
            f16x8 b1 = *(const f16x8*)&Bs[(wn * 64 + 16 + lr) * 64 + csl];
            f16x8 b2 = *(const f16x8*)&Bs[(wn * 64 + 32 + lr) * 64 + csl];
            f16x8 b3 = *(const f16x8*)&Bs[(wn * 64 + 48 + lr) * 64 + csl];
#define MFMA_ROW(MT) { \
            f16x8 av = *(const f16x8*)&As[(wm * 128 + MT * 16 + lr) * 64 + csl]; \
            a##MT##_0 = __builtin_amdgcn_mfma_f32_16x16x32_f16(av, b0, a##MT##_0, 0, 0, 0); \
            a##MT##_1 = __builtin_amdgcn_mfma_f32_16x16x32_f16(av, b1, a##MT##_1, 0, 0, 0); \
            a##MT##_2 = __builtin_amdgcn_mfma_f32_16x16x32_f16(av, b2, a##MT##_2, 0, 0, 0); \
            a##MT##_3 = __builtin_amdgcn_mfma_f32_16x16x32_f16(av, b3, a##MT##_3, 0, 0, 0); }
            MFMA_ROW(0) MFMA_ROW(1) MFMA_ROW(2) MFMA_ROW(3)
            MFMA_ROW(4) MFMA_ROW(5) MFMA_ROW(6) MFMA_ROW(7)
#undef MFMA_ROW
        }
        __builtin_amdgcn_s_setprio(0);
        __syncthreads();   // drains stage(t+1) loads + read-before-overwrite
        buf ^= 1;
    }

#define EPI_ROW(MT) { \
    int gr0 = m0 + wm * 128 + MT * 16 + lk * 4; \
    epi_frag<MODE>(a##MT##_0, gr0, n0 + wn * 64 +  0 + lr, qo, gko, ko, vo, sgo, bg, out); \
    epi_frag<MODE>(a##MT##_1, gr0, n0 + wn * 64 + 16 + lr, qo, gko, ko, vo, sgo, bg, out); \
    epi_frag<MODE>(a##MT##_2, gr0, n0 + wn * 64 + 32 + lr, qo, gko, ko, vo, sgo, bg, out); \
    epi_frag<MODE>(a##MT##_3, gr0, n0 + wn * 64 + 48 + lr, qo, gko, ko, vo, sgo, bg, out); }
    EPI_ROW(0) EPI_ROW(1) EPI_ROW(2) EPI_ROW(3)
    EPI_ROW(4) EPI_ROW(5) EPI_ROW(6) EPI_ROW(7)
#undef EPI_ROW
}

// ---------------- pass1: per-chunk increment M_c = sum_s k_s e^{G_C - G_s} v_s^T ----------------
__global__ __launch_bounds__(64) void k_pass1(const u16* __restrict__ gkb,
                                              const u16* __restrict__ kb,
                                              const u16* __restrict__ vb,
                                              float* __restrict__ Mo,
                                              float* __restrict__ eGC) {
    __shared__ __align__(16) float kkT[64 * 32];  // [t][i] fp32
    int bhc = blockIdx.x;
    int c = bhc & 127, bh = bhc >> 7;
    int h = bh & 15, b = bh >> 4;
    int m0 = b * LSEQ + c * 64;
    int lane = threadIdx.x;
    if (lane < 32) {
        int i = lane;
        size_t base = (size_t)m0 * 512 + h * 32 + i;
        float G = 0.f;
        for (int t = 0; t < 64; t++) {
            G += h2f(gkb[base + (size_t)t * 512]);
            G = fmaxf(G, -60.f);
            kkT[t * 32 + i] = h2f(kb[base + (size_t)t * 512]) * __expf(-G);
        }
        eGC[bhc * 32 + i] = __expf(G);
    }
    __syncthreads();
    float Ma[32];
#pragma unroll
    for (int i = 0; i < 32; i++) Ma[i] = 0.f;
    size_t vbase = (size_t)m0 * 1024 + h * 64 + lane;
    for (int t = 0; t < 64; t++) {
        float vj = h2f(vb[vbase + (size_t)t * 1024]);
#pragma unroll
        for (int i4 = 0; i4 < 32; i4 += 4) {
            f32x4 kk4 = *(const f32x4*)&kkT[t * 32 + i4];
            Ma[i4 + 0] += kk4[0] * vj;
            Ma[i4 + 1] += kk4[1] * vj;
            Ma[i4 + 2] += kk4[2] * vj;
            Ma[i4 + 3] += kk4[3] * vj;
        }
    }
    size_t mb = (size_t)bhc * 2048 + lane;
#pragma unroll
    for (int i = 0; i < 32; i++) Mo[mb + i * 64] = Ma[i];
}

// ---------------- pass2: chunk-level recurrence (sequential over 128 chunks) ----------------
__global__ __launch_bounds__(64) void k_pass2(float* Mbuf, float* Sbuf,
                                              const float* __restrict__ eGC,
                                              float* __restrict__ state_out, int aliased) {
    int bh = blockIdx.x;
    int j = threadIdx.x;
    float S[32];
#pragma unroll
    for (int i = 0; i < 32; i++) S[i] = 0.f;
    for (int c = 0; c < NCH; c++) {
        size_t base = ((size_t)bh * NCH + c) * 2048;
        float mv[32], ev[32];
#pragma unroll
        for (int i = 0; i < 32; i++) mv[i] = Mbuf[base + i * 64 + j];
#pragma unroll
        for (int i = 0; i < 32; i++) ev[i] = eGC[(bh * NCH + c) * 32 + i];
        if (aliased) { asm volatile("s_waitcnt vmcnt(0)" ::: "memory"); }
#pragma unroll
        for (int i = 0; i < 32; i++) Sbuf[base + i * 64 + j] = S[i];  // chunk-START state
#pragma unroll
        for (int i = 0; i < 32; i++) S[i] = (S[i] + mv[i]) * ev[i];
    }
    size_t so = (size_t)bh * 2048 + j;
#pragma unroll
    for (int i = 0; i < 32; i++) state_out[so + i * 64] = S[i];
}

// ---------------- pass3: intra-chunk outputs + aug + groupnorm + silu-gate ----------------
__global__ __launch_bounds__(64) void k_pass3(const u16* __restrict__ qb,
                                              const u16* __restrict__ gkb,
                                              const u16* __restrict__ kb,
                                              const u16* __restrict__ vb,
                                              const u16* __restrict__ sgb,
                                              const float* __restrict__ Sbuf,
                                              const float* __restrict__ aug,
                                              u16* __restrict__ PRE) {
    __shared__ __align__(16) float qqT[64 * 32];  // [t][i] fp32
    __shared__ __align__(16) float kkT[64 * 32];
    __shared__ float awl[64];
    int bhc = blockIdx.x;
    int c = bhc & 127, bh = bhc >> 7;
    int h = bh & 15, b = bh >> 4;
    int m0 = b * LSEQ + c * 64;
    int lane = threadIdx.x;
    const float scale = 0.17677669529663689f;  // 1/sqrt(32)
    if (lane < 32) {
        int i = lane;
        float augi = aug[h * 32 + i];
        size_t base = (size_t)m0 * 512 + h * 32 + i;
        float G = 0.f;
        for (int t = 0; t < 64; t++) {
            float gkv = h2f(gkb[base + (size_t)t * 512]);
            float qv  = h2f(qb [base + (size_t)t * 512]);
            float kv  = h2f(kb [base + (size_t)t * 512]);
            G += gkv;
            G = fmaxf(G, -60.f);
            float en = __expf(-G);
            float ep = __expf(G);
            qqT[t * 32 + i] = qv * ep * scale;
            kkT[t * 32 + i] = kv * en;
            float p = qv * kv * augi;  // aug uses raw q,k
            p += __shfl_xor(p, 1);
            p += __shfl_xor(p, 2);
            p += __shfl_xor(p, 4);
            p += __shfl_xor(p, 8);
            p += __shfl_xor(p, 16);
            if (i == 0) awl[t] = p;
        }
    }
    __syncthreads();
    float T[32];
    size_t sb = (size_t)bhc * 2048 + lane;
#pragma unroll
    for (int i = 0; i < 32; i++) T[i] = Sbuf[sb + i * 64];
    size_t vbase = (size_t)m0 * 1024 + h * 64 + lane;
    for (int t = 0; t < 64; t++) {
        float vj  = h2f(vb [vbase + (size_t)t * 1024]);
        float sgj = h2f(sgb[vbase + (size_t)t * 1024]);
        float aw = awl[t];
        float o = 0.f;
#pragma unroll
        for (int i4 = 0; i4 < 32; i4 += 4) {
            f32x4 kk4 = *(const f32x4*)&kkT[t * 32 + i4];
            f32x4 qq4 = *(const f32x4*)&qqT[t * 32 + i4];
#pragma unroll
            for (int e = 0; e < 4; e++) {
                T[i4 + e] += kk4[e] * vj;    // T_t = S_c + sum kk v
                o += qq4[e] * T[i4 + e];     // o_t = qq_t . T_t
            }
        }
        o += 1.f / (1.f + __expf(-aw * vj));       // + sigmoid(aug_w * v)
        // group norm over dv=64 (all 64 lanes)
        float s1 = o, s2 = o * o;
#pragma unroll
        for (int msk = 1; msk < 64; msk <<= 1) {
            s1 += __shfl_xor(s1, msk);
            s2 += __shfl_xor(s2, msk);
        }
        float mu = s1 * 0.015625f;
        float var = s2 * 0.015625f - mu * mu;
        float on = (o - mu) * rsqrtf(fmaxf(var, 0.f) + 1e-5f);
        PRE[vbase + (size_t)t * 1024] = f2h(on * sgj);
    }
}

// ---------------- host launch ----------------
extern "C" void kernel_launch(void* const* d_in, const int* in_sizes, int n_in,
                              void* d_out, int out_size, void* d_ws, size_t ws_size,
                              hipStream_t stream) {
    (void)in_sizes; (void)n_in; (void)out_size;
    const float* x      = (const float*)d_in[0];
    const float* conv_w = (const float*)d_in[1];
    const float* Wq     = (const float*)d_in[2];
    const float* Wkg    = (const float*)d_in[3];
    const float* Wv     = (const float*)d_in[4];
    const float* Wg     = (const float*)d_in[5];
    const float* bg     = (const float*)d_in[6];
    const float* Wout   = (const float*)d_in[7];
    const float* aug    = (const float*)d_in[8];

    char* ws = (char*)d_ws;
    u16*   xb    = (u16*)  (ws + 0);            // 134217728 B (also PRE later)
    u16*   Wcat  = (u16*)  (ws + 134217728);    //   6291456
    u16*   WoutT = (u16*)  (ws + 140509184);    //   2097152
    u16*   qb    = (u16*)  (ws + 142606336);    //  67108864
    u16*   gkb   = (u16*)  (ws + 209715200);    //  67108864
    u16*   kbuf  = (u16*)  (ws + 276824064);    //  67108864
    u16*   sgb   = (u16*)  (ws + 343932928);    // 134217728
    float* Mbuf  = (float*)(ws + 478150656);    // 134217728
    float* eGC   = (float*)(ws + 612368384);    //   2097152
    float* Sb    = (float*)(ws + 614465536);    // 134217728 (optional)
    const size_t REQ_FULL = 748683264ull;
    int aliased = (ws_size < REQ_FULL) ? 1 : 0;
    float* Sbuf = aliased ? Mbuf : Sb;

    float* out = (float*)d_out;
    float* state_out = out + 67108864;
    u16* vb = (u16*)d_out;  // v (f16) lives in out region until GEMM2 overwrites it

    k_conv_silu<<<dim3(65536), dim3(256), 0, stream>>>(x, conv_w, xb);
    k_packW<<<dim3(16384), dim3(256), 0, stream>>>(Wq, Wkg, Wv, Wg, Wout, Wcat, WoutT);
    k_gemm_bt<1><<<dim3(3072), dim3(512), 0, stream>>>(xb, Wcat, 12,
                                                       qb, gkb, kbuf, vb, sgb, bg, nullptr);
    k_pass1<<<dim3(16384), dim3(64), 0, stream>>>(gkb, kbuf, vb, Mbuf, eGC);
    k_pass2<<<dim3(128), dim3(64), 0, stream>>>(Mbuf, Sbuf, eGC, state_out, aliased);
    k_pass3<<<dim3(16384), dim3(64), 0, stream>>>(qb, gkb, kbuf, vb, sgb, Sbuf, aug, xb /*PRE*/);
    k_gemm_bt<2><<<dim3(1024), dim3(512), 0, stream>>>(xb, WoutT, 4,
                                                       nullptr, nullptr, nullptr, nullptr, nullptr, nullptr, out);
}